// Round 7
// baseline (202.497 us; speedup 1.0000x reference)
//
#include <hip/hip_runtime.h>

#define BATCH   131072
#define NHID    128
#define KDIM    256     // n_in + n_hid
#define BM      32      // batch rows per tile
#define TPB     512     // 8 waves
#define NBLK    256     // persistent blocks (1 per CU)
#define NTILE   (BATCH / BM)     // 4096
#define TPBLK   (NTILE / NBLK)   // 16 tiles per block

#define AS_BYTES  (BM * KDIM * 4)      // 32768: fp32 A-tile
#define HS_BYTES  (BM * NHID * 2)      // 8192:  bf16 h-tile
#define LDS_TOTAL (2 * AS_BYTES + 2 * HS_BYTES)   // 81920

typedef __bf16 bf16_t;
typedef __bf16 bf16x4 __attribute__((ext_vector_type(4)));
typedef __bf16 bf16x8 __attribute__((ext_vector_type(8)));
typedef float  f32x4  __attribute__((ext_vector_type(4)));

#define LDS_AS3(p)  ((__attribute__((address_space(3))) void*)(p))
#define GLB_AS1(p)  ((const __attribute__((address_space(1))) void*)(p))

__device__ __forceinline__ float fsigmoid(float v) {
    return __builtin_amdgcn_rcpf(1.0f + __builtin_amdgcn_exp2f(v * -1.44269504f));
}
__device__ __forceinline__ float ftanh(float v) {
    return __builtin_fmaf(-2.0f,
        __builtin_amdgcn_rcpf(1.0f + __builtin_amdgcn_exp2f(v * 2.88539008f)), 1.0f);
}
__device__ __forceinline__ f32x4 vsig(f32x4 v) {
    f32x4 r;
    #pragma unroll
    for (int i = 0; i < 4; ++i) r[i] = fsigmoid(v[i]);
    return r;
}
__device__ __forceinline__ f32x4 vtanh(f32x4 v) {
    f32x4 r;
    #pragma unroll
    for (int i = 0; i < 4; ++i) r[i] = ftanh(v[i]);
    return r;
}

// Pack W4p[p][k] (bf16) with p = w*64 + t*16 + c  ->  gate t, output col j = w*16 + c.
__global__ void prep_kernel(const float* __restrict__ Wf, const float* __restrict__ Wi,
                            const float* __restrict__ Wc, const float* __restrict__ Wo,
                            const float* __restrict__ bfp, const float* __restrict__ bip,
                            const float* __restrict__ bcp, const float* __restrict__ bop,
                            const float* __restrict__ Wfc,
                            bf16_t* __restrict__ W4p, float* __restrict__ b4p,
                            bf16_t* __restrict__ Wfcb)
{
    int id = blockIdx.x * 256 + threadIdx.x;
    if (id < 512 * 256) {
        int p = id >> 8, k = id & 255;
        int w = p >> 6, t = (p >> 4) & 3, c = p & 15;
        int j = w * 16 + c;
        const float* W = (t == 0) ? Wf : (t == 1) ? Wi : (t == 2) ? Wc : Wo;
        W4p[id] = (bf16_t)W[j * 256 + k];
        if (k == 0) {
            const float* bs = (t == 0) ? bfp : (t == 1) ? bip : (t == 2) ? bcp : bop;
            b4p[p] = bs[j];
        }
    } else {
        int id2 = id - 512 * 256;
        if (id2 < 128 * 128) Wfcb[id2] = (bf16_t)Wfc[id2];
    }
}

__global__ __launch_bounds__(TPB, 2) void lstm_fused(
    const float* __restrict__ x, const float* __restrict__ hidden, const float* __restrict__ ctx,
    const bf16_t* __restrict__ W4p, const float* __restrict__ b4p,
    const bf16_t* __restrict__ Wfcb, const float* __restrict__ bfc,
    float* __restrict__ out, float* __restrict__ hid_out, float* __restrict__ ctx_out)
{
    // dynamic LDS: As[2] fp32 [32][256] (source-XOR-swizzled), Hs[2] bf16 [32][128]
    extern __shared__ __align__(16) char smem[];

    const int tid  = threadIdx.x;
    const int lane = tid & 63;
    const int wv   = tid >> 6;     // 0..7
    const int l16  = lane & 15;
    const int lq   = lane >> 4;    // 0..3
    const int tile0 = blockIdx.x * TPBLK;
    const int colb  = wv * 16 + lq * 4;     // lane's 4 consecutive output cols

    // ---- resident weights: B1 = wave's 64 packed gate-rows (A-operand) ----
    bf16x8 B1[32];   // [pm*8 + ks]
    {
        const bf16_t* Bp = W4p + (wv * 64 + l16) * 256 + lq * 8;
        #pragma unroll
        for (int pm = 0; pm < 4; ++pm)
            #pragma unroll
            for (int ks = 0; ks < 8; ++ks)
                B1[pm * 8 + ks] = *(const bf16x8*)(Bp + pm * 16 * 256 + ks * 32);
    }
    bf16x8 b2r[4];
    {
        const bf16_t* B2 = Wfcb + (wv * 16 + l16) * 128 + lq * 8;
        #pragma unroll
        for (int ks = 0; ks < 4; ++ks) b2r[ks] = *(const bf16x8*)(B2 + ks * 32);
    }
    const f32x4 bf4  = *(const f32x4*)(b4p + wv * 64 +  0 + lq * 4);
    const f32x4 bi4  = *(const f32x4*)(b4p + wv * 64 + 16 + lq * 4);
    const f32x4 bc4  = *(const f32x4*)(b4p + wv * 64 + 32 + lq * 4);
    const f32x4 bo4  = *(const f32x4*)(b4p + wv * 64 + 48 + lq * 4);
    const f32x4 bfc4 = *(const f32x4*)(bfc + colb);

    // per-lane source-swizzle pieces for gload_lds staging (4 rows per wave)
    // row r: LDS[r][q] = cat_row[q ^ ((r&15)<<4)]  (q = lane*16, 16B granules)
    f32x4 ctxA[2], ctxB[2];

    // ---- stage issue helper (tile tt -> buffer An) ----
    // each wave stages rows wv*4 .. wv*4+3 ; one gload_lds (16B/lane) per row
    #define STAGE_TILE(An, tt) do {                                             \
        const int rowb = (tt) * BM;                                             \
        _Pragma("unroll")                                                       \
        for (int i = 0; i < 4; ++i) {                                           \
            const int r = wv * 4 + i;                                           \
            const int qs = (lane * 16) ^ ((r & 15) << 4);                       \
            const char* sp = (qs < 512)                                         \
                ? ((const char*)hidden + (size_t)(rowb + r) * 512 + qs)         \
                : ((const char*)x      + (size_t)(rowb + r) * 512 + (qs - 512));\
            __builtin_amdgcn_global_load_lds(GLB_AS1(sp),                       \
                LDS_AS3((An) + r * 1024), 16, 0, 0);                            \
        }                                                                       \
    } while (0)

    // ---- prologue: stage tile0 -> As[0]; ctxA <- tile0 ----
    STAGE_TILE(smem, tile0 - tile0 + tile0 * 0 + tile0);   // tile0 (absolute row base)
    {
        const float* cp = ctx + (size_t)(tile0 * BM) * NHID + colb;
        ctxA[0] = *(const f32x4*)(cp + (size_t)l16 * NHID);
        ctxA[1] = *(const f32x4*)(cp + (size_t)(16 + l16) * NHID);
    }
    __syncthreads();   // drains prologue staging (vmcnt 0)

    for (int t = 0; t < TPBLK; ++t) {
        const int P = t & 1;
        const int row0 = (tile0 + t) * BM;
        char* Asb = smem + P * AS_BYTES;
        char* Hsb = smem + 2 * AS_BYTES + P * HS_BYTES;

        // ---- TOP: issue tile t+1 staging (async, register-free) + ctx loads ----
        {
            const int tn = (t + 1 < TPBLK) ? (tile0 + t + 1) : (tile0 + TPBLK - 1);
            char* An = smem + (1 - P) * AS_BYTES;
            STAGE_TILE(An, tn);
            const float* cp = ctx + (size_t)(tn * BM) * NHID + colb;
            ctxB[0] = *(const f32x4*)(cp + (size_t)l16 * NHID);
            ctxB[1] = *(const f32x4*)(cp + (size_t)(16 + l16) * NHID);
        }

        // ---- GEMM1 (transposed): acc[pm][bn] ; A=weights(regs), B=batch(LDS fp32) ----
        f32x4 acc[4][2];
        #pragma unroll
        for (int pm = 0; pm < 4; ++pm) {
            acc[pm][0] = f32x4{0.f, 0.f, 0.f, 0.f};
            acc[pm][1] = f32x4{0.f, 0.f, 0.f, 0.f};
        }
        #pragma unroll
        for (int ks = 0; ks < 8; ++ks) {
            const int kb = ks * 128 + lq * 32;
            bf16x8 a[2];
            #pragma unroll
            for (int bn = 0; bn < 2; ++bn) {
                const int rr = bn * 16 + l16;
                const char* base = Asb + rr * 1024;
                const int swz = (rr & 15) << 4;
                f32x4 f0 = *(const f32x4*)(base + (kb ^ swz));
                f32x4 f1 = *(const f32x4*)(base + ((kb + 16) ^ swz));
                a[bn][0] = (bf16_t)f0.x; a[bn][1] = (bf16_t)f0.y;
                a[bn][2] = (bf16_t)f0.z; a[bn][3] = (bf16_t)f0.w;
                a[bn][4] = (bf16_t)f1.x; a[bn][5] = (bf16_t)f1.y;
                a[bn][6] = (bf16_t)f1.z; a[bn][7] = (bf16_t)f1.w;
            }
            #pragma unroll
            for (int pm = 0; pm < 4; ++pm) {
                acc[pm][0] = __builtin_amdgcn_mfma_f32_16x16x32_bf16(B1[pm * 8 + ks], a[0], acc[pm][0], 0, 0, 0);
                acc[pm][1] = __builtin_amdgcn_mfma_f32_16x16x32_bf16(B1[pm * 8 + ks], a[1], acc[pm][1], 0, 0, 0);
            }
        }

        // ---- fused LSTM elementwise (all gates in-lane); stores DEFERRED ----
        f32x4 cn[2], hn[2];
        #pragma unroll
        for (int bn = 0; bn < 2; ++bn) {
            const f32x4 fv = vsig(acc[0][bn] + bf4);
            const f32x4 iv = vsig(acc[1][bn] + bi4);
            const f32x4 cv = vtanh(acc[2][bn] + bc4);
            const f32x4 ov = vsig(acc[3][bn] + bo4);
            cn[bn] = fv * ctxA[bn] + iv * cv;
            hn[bn] = ov * vtanh(cn[bn]);
            bf16x4 hb;
            hb[0] = (bf16_t)hn[bn].x; hb[1] = (bf16_t)hn[bn].y;
            hb[2] = (bf16_t)hn[bn].z; hb[3] = (bf16_t)hn[bn].w;
            const int rh = bn * 16 + l16;
            *(bf16x4*)(Hsb + rh * 256 + ((wv * 32 + lq * 8) ^ ((rh & 15) << 4))) = hb;
        }
        ctxA[0] = ctxB[0];
        ctxA[1] = ctxB[1];

        __syncthreads();   // drains: stage(t+1) (issued ~GEMM1 ago), stores(t-1) (a tile ago)

        // ---- post-barrier: stores of tile t (acks drain at NEXT barrier) ----
        #pragma unroll
        for (int bn = 0; bn < 2; ++bn) {
            const size_t grow = (size_t)(row0 + bn * 16 + l16) * NHID + colb;
            *(f32x4*)(ctx_out + grow) = cn[bn];
            *(f32x4*)(hid_out + grow) = hn[bn];
        }

        // ---- GEMM2 (transposed): out^T = Wfc . h^T ----
        f32x4 acc2[2];
        acc2[0] = f32x4{0.f, 0.f, 0.f, 0.f};
        acc2[1] = f32x4{0.f, 0.f, 0.f, 0.f};
        #pragma unroll
        for (int ks = 0; ks < 4; ++ks) {
            const int kb = ks * 64 + lq * 16;
            bf16x8 h0, h1;
            {
                const int rr = l16;
                h0 = *(const bf16x8*)(Hsb + rr * 256 + (kb ^ ((rr & 15) << 4)));
            }
            {
                const int rr = 16 + l16;
                h1 = *(const bf16x8*)(Hsb + rr * 256 + (kb ^ ((rr & 15) << 4)));
            }
            acc2[0] = __builtin_amdgcn_mfma_f32_16x16x32_bf16(b2r[ks], h0, acc2[0], 0, 0, 0);
            acc2[1] = __builtin_amdgcn_mfma_f32_16x16x32_bf16(b2r[ks], h1, acc2[1], 0, 0, 0);
        }
        #pragma unroll
        for (int bn = 0; bn < 2; ++bn) {
            const size_t grow = (size_t)(row0 + bn * 16 + l16) * NHID + colb;
            *(f32x4*)(out + grow) = acc2[bn] + bfc4;
        }
    }
    #undef STAGE_TILE
}

extern "C" void kernel_launch(void* const* d_in, const int* in_sizes, int n_in,
                              void* d_out, int out_size, void* d_ws, size_t ws_size,
                              hipStream_t stream) {
    const float* x      = (const float*)d_in[0];
    const float* hidden = (const float*)d_in[1];
    const float* ctx    = (const float*)d_in[2];
    const float* Wf     = (const float*)d_in[3];
    const float* bfp    = (const float*)d_in[4];
    const float* Wi     = (const float*)d_in[5];
    const float* bip    = (const float*)d_in[6];
    const float* Wc     = (const float*)d_in[7];
    const float* bcp    = (const float*)d_in[8];
    const float* Wo     = (const float*)d_in[9];
    const float* bop    = (const float*)d_in[10];
    const float* Wfc    = (const float*)d_in[11];
    const float* bfc    = (const float*)d_in[12];

    bf16_t* W4p  = (bf16_t*)d_ws;                                   // 262144 B
    float*  b4p  = (float*)((char*)d_ws + 512 * 256 * 2);           // 2048 B
    bf16_t* Wfcb = (bf16_t*)((char*)d_ws + 512 * 256 * 2 + 2048);   // 32768 B

    static bool attr_set = false;
    hipFuncSetAttribute((const void*)lstm_fused,
                        hipFuncAttributeMaxDynamicSharedMemorySize, LDS_TOTAL);
    (void)attr_set;

    prep_kernel<<<576, 256, 0, stream>>>(Wf, Wi, Wc, Wo, bfp, bip, bcp, bop, Wfc,
                                         W4p, b4p, Wfcb);

    float* outp = (float*)d_out;
    lstm_fused<<<NBLK, TPB, LDS_TOTAL, stream>>>(
        x, hidden, ctx, W4p, b4p, Wfcb, bfc,
        outp,
        outp + (size_t)BATCH * NHID,
        outp + 2 * (size_t)BATCH * NHID);
}